// Round 4
// baseline (588.481 us; speedup 1.0000x reference)
//
#include <hip/hip_runtime.h>
#include <math.h>

#define EPSF 1.1920928955078125e-07f

constexpr int N_ = 8, C_ = 8, F_ = 257, T_ = 1500, A_ = 512;
constexpr int NF = N_ * F_;          // 2056
constexpr int CS = F_ * T_;          // channel stride in x (385500)
constexpr int CS4 = CS / 4;          // 96375
constexpr int T4 = T_ / 4;           // 375

// ---- ws layout (float offsets) ----
constexpr size_t OFF_MAX  = 0;                       // 2056
constexpr size_t OFF_SUM  = 2056;                    // 2056
constexpr size_t OFF_MT   = 4352;                    // N*F*T = 3084000
constexpr size_t OFF_RS   = (OFF_MT + (size_t)N_*F_*T_ + 63) & ~(size_t)63; // NF*64*2
constexpr size_t OFF_RN   = OFF_RS + (size_t)NF*64*2;
constexpr size_t OFF_FEAT = OFF_RN + (size_t)NF*64*2;   // N*C*F
constexpr size_t OFF_G    = OFF_FEAT + (size_t)N_*C_*F_; // 64
constexpr size_t OFF_WC   = OFF_G + 64;                  // NF*8*2

__device__ __forceinline__ float get4(const float4& v, int k) {
  switch (k) { case 0: return v.x; case 1: return v.y; case 2: return v.z; default: return v.w; }
}

// fused transpose + per-(n,f) stats: m[n][t][f] -> mt[n][f][t], maxabs, summ (atomics)
__global__ void mask_prep(const float* __restrict__ m, float* __restrict__ mt,
                          float* __restrict__ maxabs, float* __restrict__ summ) {
  __shared__ float tile[32][33];
  int n = blockIdx.z;
  int f0 = blockIdx.x * 32, t0 = blockIdx.y * 32;
  int tx = threadIdx.x, ty = threadIdx.y;  // 32 x 8
  #pragma unroll
  for (int r = 0; r < 4; ++r) {
    int t = t0 + ty + r * 8, f = f0 + tx;
    tile[ty + r * 8][tx] = (t < T_ && f < F_) ? m[((size_t)n * T_ + t) * F_ + f] : 0.f;
  }
  __syncthreads();
  #pragma unroll
  for (int r = 0; r < 4; ++r) {
    int f = f0 + ty + r * 8, t = t0 + tx;
    float v = tile[tx][ty + r * 8];
    if (t < T_ && f < F_) mt[((size_t)n * F_ + f) * T_ + t] = v;
    // reduce over tx (32 lanes; m >= 0 so max-with-0 padding is safe)
    float lm = v, ls = v;
    #pragma unroll
    for (int s = 1; s < 32; s <<= 1) {
      lm = fmaxf(lm, __shfl_xor(lm, s));
      ls += __shfl_xor(ls, s);
    }
    if (tx == 0 && f < F_) {
      atomicMax((unsigned int*)(maxabs + n * F_ + f), __float_as_uint(lm));
      atomicAdd(summ + n * F_ + f, ls);
    }
  }
}

// one wave per (n,f): float4 streaming accumulation of full & m-weighted outer products;
// finalize Rs / Rn_reg and the channel-attention feature row.
// NOTE: needs ~128 accumulator VGPRs + 64 staging VGPRs. __launch_bounds__(64)
// (no min-waves clamp): a (64,2) clamp capped VGPRs at 128 and spilled ~135 MB
// of scratch traffic per dispatch (round-3 counters: WRITE_SIZE 91 MB).
// Grid supplies only 2 waves/SIMD anyway, so the clamp bought nothing.
__global__ __launch_bounds__(64) void covar_kernel(
    const float* __restrict__ xr, const float* __restrict__ xi,
    const float* __restrict__ mt, const float* __restrict__ maxabs,
    const float* __restrict__ summ, float* __restrict__ Rs, float* __restrict__ Rn,
    float* __restrict__ feat) {
  int item = blockIdx.x;           // n*F + f
  int lane = threadIdx.x;
  int n = item / F_, f = item % F_;
  size_t b4 = (((size_t)(n * C_) * CS) + (size_t)f * T_) >> 2;  // float4 units
  const float4* pxr = (const float4*)xr;
  const float4* pxi = (const float4*)xi;
  const float4* m4  = (const float4*)(mt + (size_t)item * T_);

  float fr[36], wr[36], fi[28], wi[28];
  #pragma unroll
  for (int p = 0; p < 36; ++p) { fr[p] = 0.f; wr[p] = 0.f; }
  #pragma unroll
  for (int p = 0; p < 28; ++p) { fi[p] = 0.f; wi[p] = 0.f; }

  #pragma unroll
  for (int pass = 0; pass < 6; ++pass) {
    int tq = pass * 64 + lane;     // float4 index within the T row
    if (tq < T4) {
      float4 mv = m4[tq];
      float4 ar[8], ai[8];
      #pragma unroll
      for (int c = 0; c < 8; ++c) {
        ar[c] = pxr[b4 + (size_t)c * CS4 + tq];
        ai[c] = pxi[b4 + (size_t)c * CS4 + tq];
      }
      #pragma unroll
      for (int k = 0; k < 4; ++k) {
        float mvk = get4(mv, k);
        float re[8], im[8];
        #pragma unroll
        for (int c = 0; c < 8; ++c) { re[c] = get4(ar[c], k); im[c] = get4(ai[c], k); }
        int p = 0, q = 0;
        #pragma unroll
        for (int c = 0; c < 8; ++c) {
          #pragma unroll
          for (int d = 0; d <= c; ++d) {
            float pre = re[c] * re[d] + im[c] * im[d];
            fr[p] += pre;
            wr[p] = fmaf(mvk, pre, wr[p]);
            if (d != c) {
              float pim = im[c] * re[d] - re[c] * im[d];
              fi[q] += pim;
              wi[q] = fmaf(mvk, pim, wi[q]);
              ++q;
            }
            ++p;
          }
        }
      }
    }
  }

  // butterfly reduce across the wave
  #pragma unroll
  for (int s = 1; s < 64; s <<= 1) {
    #pragma unroll
    for (int p = 0; p < 36; ++p) { fr[p] += __shfl_xor(fr[p], s); wr[p] += __shfl_xor(wr[p], s); }
    #pragma unroll
    for (int p = 0; p < 28; ++p) { fi[p] += __shfl_xor(fi[p], s); wi[p] += __shfl_xor(wi[p], s); }
  }

  __shared__ float s_fr[36], s_wr[36], s_fi[28], s_wi[28];
  if (lane == 0) {
    #pragma unroll
    for (int p = 0; p < 36; ++p) { s_fr[p] = fr[p]; s_wr[p] = wr[p]; }
    #pragma unroll
    for (int p = 0; p < 28; ++p) { s_fi[p] = fi[p]; s_wi[p] = wi[p]; }
  }
  __syncthreads();

  float inv  = 1.f / (maxabs[item] + EPSF);
  float msum = summ[item] * inv;
  float dens = fmaxf(msum, EPSF);
  float denn = fmaxf((float)T_ - msum, EPSF);

  int c = lane >> 3, d = lane & 7;
  int cc = max(c, d), dd = min(c, d);
  int p = cc * (cc + 1) / 2 + dd;
  bool offd = (c != d);
  float sgn = (d > c) ? -1.f : 1.f;
  float swr = s_wr[p], sfr = s_fr[p], swi = 0.f, sfi = 0.f;
  if (offd) {
    int q = cc * (cc - 1) / 2 + dd;
    swi = sgn * s_wi[q];
    sfi = sgn * s_fi[q];
  }
  float nsr = swr * inv, nsi = swi * inv;          // masked (speech) numerator
  float rs_re = nsr / dens, rs_im = nsi / dens;
  float rn_re = (sfr - nsr) / denn, rn_im = (sfi - nsi) / denn;
  if (!offd) rn_re += EPSF;                        // Rn_reg = Rn + eps*I

  ((float2*)Rs)[(size_t)item * 64 + lane] = make_float2(rs_re, rs_im);
  ((float2*)Rn)[(size_t)item * 64 + lane] = make_float2(rn_re, rn_im);

  // feat[n][c][f] = |sum_{d!=c} Rs[c][d]| / 7  (reduce over d within 8-lane groups)
  float offr = offd ? rs_re : 0.f, offi = offd ? rs_im : 0.f;
  #pragma unroll
  for (int s = 1; s < 8; s <<= 1) { offr += __shfl_xor(offr, s); offi += __shfl_xor(offi, s); }
  if (d == 0)
    feat[((size_t)(n * C_ + c)) * F_ + f] = sqrtf(offr * offr + offi * offi) * (1.f / 7.f);
}

// g[n*8+c] = sum_a tanh(feat.proj_w[a] + proj_b[a]) * gvec_w[a] + gvec_b
__global__ __launch_bounds__(256) void proj_kernel(
    const float* __restrict__ feat, const float* __restrict__ pw,
    const float* __restrict__ pb, const float* __restrict__ gw,
    const float* __restrict__ gb, float* __restrict__ g) {
  __shared__ float sfeat[F_];
  __shared__ float red[256];
  int nc = blockIdx.x;
  for (int i = threadIdx.x; i < F_; i += 256) sfeat[i] = feat[(size_t)nc * F_ + i];
  __syncthreads();
  float acc = 0.f;
  for (int a = threadIdx.x; a < A_; a += 256) {
    const float* wrow = pw + (size_t)a * F_;
    float s = 0.f;
    #pragma unroll 4
    for (int ff = 0; ff < F_; ++ff) s += sfeat[ff] * wrow[ff];
    acc += tanhf(s + pb[a]) * gw[a];
  }
  red[threadIdx.x] = acc;
  __syncthreads();
  for (int s = 128; s; s >>= 1) {
    if (threadIdx.x < (unsigned)s) red[threadIdx.x] += red[threadIdx.x + s];
    __syncthreads();
  }
  if (threadIdx.x == 0) g[nc] = red[0] + gb[0];
}

// 8 lanes per (n,f): Gauss-Jordan inverse of Rn_reg, then w = Rn_inv (Rs u) / tr(Rn_inv Rs); store conj(w)
__global__ __launch_bounds__(64) void mvdr_kernel(
    const float* __restrict__ Rs, const float* __restrict__ Rn,
    const float* __restrict__ g, float* __restrict__ wc) {
  int lane = threadIdx.x;
  int item = blockIdx.x * 8 + (lane >> 3);
  int r = lane & 7;
  int base = lane & ~7;
  int n = item / F_;

  const float2* RnM = (const float2*)Rn + (size_t)item * 64;
  const float2* RsM = (const float2*)Rs + (size_t)item * 64;
  float ar[8], ai[8], br[8], bi[8], rsr[8], rsi[8];
  #pragma unroll
  for (int j = 0; j < 8; ++j) {
    float2 v = RnM[r * 8 + j]; ar[j] = v.x; ai[j] = v.y;
    float2 w = RsM[r * 8 + j]; rsr[j] = w.x; rsi[j] = w.y;
    br[j] = (j == r) ? 1.f : 0.f; bi[j] = 0.f;
  }

  #pragma unroll
  for (int k = 0; k < 8; ++k) {
    if (r == k) {
      float dre = ar[k], dim = ai[k];
      float s = 1.f / (dre * dre + dim * dim);
      float cre = dre * s, cim = -dim * s;
      #pragma unroll
      for (int j = 0; j < 8; ++j) {
        float t0 = ar[j] * cre - ai[j] * cim, t1 = ar[j] * cim + ai[j] * cre;
        ar[j] = t0; ai[j] = t1;
        float u0 = br[j] * cre - bi[j] * cim, u1 = br[j] * cim + bi[j] * cre;
        br[j] = u0; bi[j] = u1;
      }
    }
    float par[8], pai[8], pbr[8], pbi[8];
    #pragma unroll
    for (int j = 0; j < 8; ++j) {
      par[j] = __shfl(ar[j], base + k); pai[j] = __shfl(ai[j], base + k);
      pbr[j] = __shfl(br[j], base + k); pbi[j] = __shfl(bi[j], base + k);
    }
    if (r != k) {
      float fre = ar[k], fim = ai[k];
      #pragma unroll
      for (int j = 0; j < 8; ++j) {
        ar[j] -= fre * par[j] - fim * pai[j];
        ai[j] -= fre * pai[j] + fim * par[j];
        br[j] -= fre * pbr[j] - fim * pbi[j];
        bi[j] -= fre * pbi[j] + fim * pbr[j];
      }
    }
  }

  float gv[8];
  #pragma unroll
  for (int d = 0; d < 8; ++d) gv[d] = g[n * 8 + d];
  float gm = gv[0];
  #pragma unroll
  for (int d = 1; d < 8; ++d) gm = fmaxf(gm, gv[d]);
  float u[8], usum = 0.f;
  #pragma unroll
  for (int d = 0; d < 8; ++d) { u[d] = expf(gv[d] - gm); usum += u[d]; }
  float uinv = 1.f / usum;
  #pragma unroll
  for (int d = 0; d < 8; ++d) u[d] *= uinv;

  float avr = 0.f, avi = 0.f;
  #pragma unroll
  for (int d = 0; d < 8; ++d) { avr += rsr[d] * u[d]; avi += rsi[d] * u[d]; }

  float wnr = 0.f, wni = 0.f;
  #pragma unroll
  for (int d = 0; d < 8; ++d) {
    float adr = __shfl(avr, base + d), adi = __shfl(avi, base + d);
    wnr += br[d] * adr - bi[d] * adi;
    wni += br[d] * adi + bi[d] * adr;
  }

  float trr = 0.f, tri = 0.f;
  #pragma unroll
  for (int d = 0; d < 8; ++d) {
    trr += br[d] * rsr[d] + bi[d] * rsi[d];
    tri += bi[d] * rsr[d] - br[d] * rsi[d];
  }
  #pragma unroll
  for (int s = 1; s < 8; s <<= 1) { trr += __shfl_xor(trr, s); tri += __shfl_xor(tri, s); }
  trr += EPSF;

  float den = trr * trr + tri * tri;
  float wre = (wnr * trr + wni * tri) / den;
  float wim = (wni * trr - wnr * tri) / den;
  ((float2*)wc)[(size_t)item * 8 + r] = make_float2(wre, -wim);  // conj(w)
}

// beam[n,f,t] = sum_c conj(w) x ; 8f x 128t tile, float4 loads, LDS transpose to (N,T,F,2)
__global__ __launch_bounds__(256) void beamform_kernel(
    const float* __restrict__ xr, const float* __restrict__ xi,
    const float* __restrict__ wc, float* __restrict__ out) {
  __shared__ float lds[128][17];
  int n = blockIdx.z;
  int fb = blockIdx.x * 8;
  int tb = blockIdx.y * 128;
  int tid = threadIdx.x;
  int q  = tid & 31;         // t-quad within tile
  int fi = tid >> 5;         // 0..7
  int f = fb + fi;
  int t = tb + q * 4;

  float4 br = make_float4(0.f, 0.f, 0.f, 0.f);
  float4 bi = make_float4(0.f, 0.f, 0.f, 0.f);
  if (f < F_ && t < T_) {    // T divisible by 4 -> whole quad valid
    size_t e4 = ((((size_t)(n * C_) * F_ + f) * T_) + t) >> 2;
    const float2* wrow = (const float2*)wc + ((size_t)n * F_ + f) * 8;
    #pragma unroll
    for (int c = 0; c < 8; ++c) {
      float4 a = ((const float4*)xr)[e4 + (size_t)c * CS4];
      float4 b = ((const float4*)xi)[e4 + (size_t)c * CS4];
      float2 w = wrow[c];
      br.x += w.x * a.x - w.y * b.x;  bi.x += w.x * b.x + w.y * a.x;
      br.y += w.x * a.y - w.y * b.y;  bi.y += w.x * b.y + w.y * a.y;
      br.z += w.x * a.z - w.y * b.z;  bi.z += w.x * b.z + w.y * a.z;
      br.w += w.x * a.w - w.y * b.w;  bi.w += w.x * b.w + w.y * a.w;
    }
  }
  int row = q * 4, col = fi * 2;
  lds[row + 0][col] = br.x; lds[row + 0][col + 1] = bi.x;
  lds[row + 1][col] = br.y; lds[row + 1][col + 1] = bi.y;
  lds[row + 2][col] = br.z; lds[row + 2][col + 1] = bi.z;
  lds[row + 3][col] = br.w; lds[row + 3][col + 1] = bi.w;
  __syncthreads();

  int col2 = tid & 15, r0 = tid >> 4;
  #pragma unroll
  for (int pass = 0; pass < 8; ++pass) {
    int rr = pass * 16 + r0;
    int tt = tb + rr;
    int ff = fb + (col2 >> 1);
    if (tt < T_ && ff < F_)
      out[(((size_t)n * T_ + tt) * F_ + ff) * 2 + (col2 & 1)] = lds[rr][col2];
  }
}

extern "C" void kernel_launch(void* const* d_in, const int* in_sizes, int n_in,
                              void* d_out, int out_size, void* d_ws, size_t ws_size,
                              hipStream_t stream) {
  const float* m  = (const float*)d_in[0];
  const float* xr = (const float*)d_in[1];
  const float* xi = (const float*)d_in[2];
  const float* pw = (const float*)d_in[3];
  const float* pb = (const float*)d_in[4];
  const float* gw = (const float*)d_in[5];
  const float* gb = (const float*)d_in[6];
  float* ws  = (float*)d_ws;
  float* out = (float*)d_out;

  float* maxabs = ws + OFF_MAX;
  float* summ   = ws + OFF_SUM;
  float* mt     = ws + OFF_MT;
  float* Rs     = ws + OFF_RS;
  float* Rn     = ws + OFF_RN;
  float* feat   = ws + OFF_FEAT;
  float* g      = ws + OFF_G;
  float* wc     = ws + OFF_WC;

  hipMemsetAsync(maxabs, 0, 4112 * sizeof(float), stream);  // maxabs + summ contiguous
  hipLaunchKernelGGL(mask_prep, dim3(9, 47, 8), dim3(32, 8), 0, stream, m, mt, maxabs, summ);
  hipLaunchKernelGGL(covar_kernel, dim3(NF), dim3(64), 0, stream, xr, xi, mt, maxabs, summ, Rs, Rn, feat);
  hipLaunchKernelGGL(proj_kernel, dim3(64), dim3(256), 0, stream, feat, pw, pb, gw, gb, g);
  hipLaunchKernelGGL(mvdr_kernel, dim3(NF / 8), dim3(64), 0, stream, Rs, Rn, g, wc);
  hipLaunchKernelGGL(beamform_kernel, dim3(33, 12, 8), dim3(256), 0, stream, xr, xi, wc, out);
}

// Round 6
// 499.258 us; speedup vs baseline: 1.1787x; 1.1787x over previous
//
#include <hip/hip_runtime.h>
#include <math.h>

#define EPSF 1.1920928955078125e-07f

constexpr int N_ = 8, C_ = 8, F_ = 257, T_ = 1500, A_ = 512;
constexpr int NF = N_ * F_;          // 2056
constexpr int CS = F_ * T_;          // channel stride in x (385500)
constexpr int CS4 = CS / 4;          // 96375
constexpr int T4 = T_ / 4;           // 375 float4s per (n,f,c) row

// ---- ws layout (float offsets) ----
constexpr size_t OFF_MAX  = 0;                       // 2056
constexpr size_t OFF_SUM  = 2056;                    // 2056
constexpr size_t OFF_MT   = 4352;                    // N*F*T
constexpr size_t OFF_RS   = (OFF_MT + (size_t)N_*F_*T_ + 63) & ~(size_t)63;
constexpr size_t OFF_RN   = OFF_RS + (size_t)NF*64*2;
constexpr size_t OFF_FEAT = OFF_RN + (size_t)NF*64*2;
constexpr size_t OFF_G    = OFF_FEAT + (size_t)N_*C_*F_;
constexpr size_t OFF_WC   = OFF_G + 64;
constexpr size_t OFF_XT   = (OFF_WC + (size_t)NF*8*2 + 63) & ~(size_t)63;
constexpr size_t XT_SZ    = (size_t)NF * T_ * 16;    // x transposed to [n][f][t][c8][re,im]

__device__ __forceinline__ float get4(const float4& v, int k) {
  switch (k) { case 0: return v.x; case 1: return v.y; case 2: return v.z; default: return v.w; }
}

// pair index maps (compile-time): re-slots p=0..35 lower-tri incl diag (c>=d),
// im-slots q=0..27 strict lower-tri (c>d)
constexpr int pc(int p) { int c = 0; while ((c + 1) * (c + 2) / 2 <= p) ++c; return c; }
constexpr int pd(int p) { return p - pc(p) * (pc(p) + 1) / 2; }
constexpr int qc(int q) { int c = 1; while (c * (c + 1) / 2 <= q) ++c; return c; }
constexpr int qd(int q) { return q - qc(q) * (qc(q) - 1) / 2; }

// per-wave slot subset: wave W owns slots W*16..W*16+15 of the 64
// (slot<36: re-pair p=slot; else: im-pair q=slot-36)
template <int W, int I> struct SS {
  static __device__ __forceinline__ void run(const float* re, const float* im, float mk,
                                             float* af, float* aw) {
    constexpr int slot = W * 16 + I;
    if constexpr (slot < 36) {
      constexpr int c = pc(slot), d = pd(slot);
      float pre = re[c] * re[d] + im[c] * im[d];
      af[I] += pre; aw[I] = fmaf(mk, pre, aw[I]);
    } else {
      constexpr int c = qc(slot - 36), d = qd(slot - 36);
      float pim = im[c] * re[d] - re[c] * im[d];
      af[I] += pim; aw[I] = fmaf(mk, pim, aw[I]);
    }
    SS<W, I + 1>::run(re, im, mk, af, aw);
  }
};
template <int W> struct SS<W, 16> {
  static __device__ __forceinline__ void run(const float*, const float*, float, float*, float*) {}
};

template <int W>
__device__ __forceinline__ void acc_chunk(const float4 (*tl)[64], int lane, float* af, float* aw) {
  float4 xv[16];
  #pragma unroll
  for (int s = 0; s < 16; ++s) xv[s] = tl[s][lane];
  float4 mv = tl[16][lane];
  #pragma unroll
  for (int k = 0; k < 4; ++k) {
    float mk = get4(mv, k);
    float re[8], im[8];
    #pragma unroll
    for (int c = 0; c < 8; ++c) { re[c] = get4(xv[c], k); im[c] = get4(xv[8 + c], k); }
    SS<W, 0>::run(re, im, mk, af, aw);
  }
}

__device__ __forceinline__ void gll16(const void* g, void* l) {
  __builtin_amdgcn_global_load_lds((const __attribute__((address_space(1))) unsigned int*)g,
                                   (__attribute__((address_space(3))) unsigned int*)l, 16, 0, 0);
}

// fused transpose + per-(n,f) stats: m[n][t][f] -> mt[n][f][t], maxabs, summ (atomics)
__global__ void mask_prep(const float* __restrict__ m, float* __restrict__ mt,
                          float* __restrict__ maxabs, float* __restrict__ summ) {
  __shared__ float tile[32][33];
  int n = blockIdx.z;
  int f0 = blockIdx.x * 32, t0 = blockIdx.y * 32;
  int tx = threadIdx.x, ty = threadIdx.y;  // 32 x 8
  #pragma unroll
  for (int r = 0; r < 4; ++r) {
    int t = t0 + ty + r * 8, f = f0 + tx;
    tile[ty + r * 8][tx] = (t < T_ && f < F_) ? m[((size_t)n * T_ + t) * F_ + f] : 0.f;
  }
  __syncthreads();
  #pragma unroll
  for (int r = 0; r < 4; ++r) {
    int f = f0 + ty + r * 8, t = t0 + tx;
    float v = tile[tx][ty + r * 8];
    if (t < T_ && f < F_) mt[((size_t)n * F_ + f) * T_ + t] = v;
    float lm = v, ls = v;
    #pragma unroll
    for (int s = 1; s < 32; s <<= 1) {
      lm = fmaxf(lm, __shfl_xor(lm, s));
      ls += __shfl_xor(ls, s);
    }
    if (tx == 0 && f < F_) {
      atomicMax((unsigned int*)(maxabs + n * F_ + f), __float_as_uint(lm));
      atomicAdd(summ + n * F_ + f, ls);
    }
  }
}

// 256-thread block per (n,f): LDS-staged (global_load_lds, double-buffered),
// pair-slots split across 4 waves; also emits x_t[n][f][t][c8][2] for beamform.
__global__ __launch_bounds__(256) void covar_kernel(
    const float* __restrict__ xr, const float* __restrict__ xi,
    const float* __restrict__ mt, const float* __restrict__ maxabs,
    const float* __restrict__ summ, float* __restrict__ Rs, float* __restrict__ Rn,
    float* __restrict__ feat, float* __restrict__ xt, int have_xt) {
  __shared__ float4 tile[2][17][64];   // [buf][stream 0..7=re,8..15=im,16=mask][t-quad]
  __shared__ float redf[64], redw[64];
  int item = blockIdx.x, tid = threadIdx.x;
  int wid = tid >> 6, lane = tid & 63;
  int n = item / F_, f = item % F_;
  size_t b4 = (size_t)(n * C_) * CS4 + (size_t)f * T4;
  const float4* pxr = (const float4*)xr;
  const float4* pxi = (const float4*)xi;
  const float4* m4  = (const float4*)(mt + (size_t)item * T_);

  float af[16], aw[16];
  #pragma unroll
  for (int i = 0; i < 16; ++i) { af[i] = 0.f; aw[i] = 0.f; }

  // stage chunk k (k=0..4 full 64 quads) into tl via async global->LDS
  auto stage = [&](int k, float4 (*tl)[64]) {
    #pragma unroll
    for (int j = 0; j < 4; ++j) {
      int s = wid * 4 + j;
      const float4* plane = (s < 8) ? (pxr + b4 + (size_t)s * CS4)
                                    : (pxi + b4 + (size_t)(s - 8) * CS4);
      gll16(plane + k * 64 + lane, &tl[s][0]);
    }
    if (wid == 0) gll16(m4 + k * 64 + lane, &tl[16][0]);
  };
  // chunk 5 partial (55 of 64 quads valid) via predicated register path
  auto stage5 = [&](float4 (*tl)[64]) {
    int t4g = 5 * 64 + lane;
    bool ok = t4g < T4;
    float4 z = make_float4(0.f, 0.f, 0.f, 0.f);
    #pragma unroll
    for (int j = 0; j < 4; ++j) {
      int s = wid * 4 + j;
      const float4* plane = (s < 8) ? (pxr + b4 + (size_t)s * CS4)
                                    : (pxi + b4 + (size_t)(s - 8) * CS4);
      tl[s][lane] = ok ? plane[t4g] : z;
    }
    if (wid == 0) tl[16][lane] = ok ? m4[t4g] : z;
  };

  stage(0, tile[0]);
  __syncthreads();
  int buf = 0;
  for (int k = 0; k < 6; ++k) {
    if (k < 4) stage(k + 1, tile[buf ^ 1]);
    else if (k == 4) stage5(tile[buf ^ 1]);
    switch (wid) {
      case 0: acc_chunk<0>(tile[buf], lane, af, aw); break;
      case 1: acc_chunk<1>(tile[buf], lane, af, aw); break;
      case 2: acc_chunk<2>(tile[buf], lane, af, aw); break;
      default: acc_chunk<3>(tile[buf], lane, af, aw); break;
    }
    if (have_xt) {
      int tg = k * 256 + tid;
      if (tg < T_) {
        int q = tid >> 2, e = tid & 3;
        float o[16];
        #pragma unroll
        for (int c = 0; c < 8; ++c) {
          o[2 * c]     = ((const float*)&tile[buf][c][q])[e];
          o[2 * c + 1] = ((const float*)&tile[buf][8 + c][q])[e];
        }
        float4* dst = (float4*)(xt + ((size_t)item * T_ + tg) * 16);
        dst[0] = make_float4(o[0], o[1], o[2], o[3]);
        dst[1] = make_float4(o[4], o[5], o[6], o[7]);
        dst[2] = make_float4(o[8], o[9], o[10], o[11]);
        dst[3] = make_float4(o[12], o[13], o[14], o[15]);
      }
    }
    __syncthreads();
    buf ^= 1;
  }

  // reduce each wave's 16 slots across its 64 lanes
  #pragma unroll
  for (int s = 1; s < 64; s <<= 1) {
    #pragma unroll
    for (int i = 0; i < 16; ++i) { af[i] += __shfl_xor(af[i], s); aw[i] += __shfl_xor(aw[i], s); }
  }
  if (lane == 0) {
    #pragma unroll
    for (int i = 0; i < 16; ++i) { redf[wid * 16 + i] = af[i]; redw[wid * 16 + i] = aw[i]; }
  }
  __syncthreads();

  if (tid < 64) {
    float inv  = 1.f / (maxabs[item] + EPSF);
    float msum = summ[item] * inv;
    float dens = fmaxf(msum, EPSF);
    float denn = fmaxf((float)T_ - msum, EPSF);

    int c = tid >> 3, d = tid & 7;
    int cc = max(c, d), dd = min(c, d);
    int p = cc * (cc + 1) / 2 + dd;
    bool offd = (c != d);
    float sgn = (d > c) ? -1.f : 1.f;
    float sfr = redf[p], swr = redw[p], sfi = 0.f, swi = 0.f;
    if (offd) {
      int q = cc * (cc - 1) / 2 + dd;
      sfi = sgn * redf[36 + q];
      swi = sgn * redw[36 + q];
    }
    float nsr = swr * inv, nsi = swi * inv;
    float rs_re = nsr / dens, rs_im = nsi / dens;
    float rn_re = (sfr - nsr) / denn, rn_im = (sfi - nsi) / denn;
    if (!offd) rn_re += EPSF;

    ((float2*)Rs)[(size_t)item * 64 + tid] = make_float2(rs_re, rs_im);
    ((float2*)Rn)[(size_t)item * 64 + tid] = make_float2(rn_re, rn_im);

    float offr = offd ? rs_re : 0.f, offi = offd ? rs_im : 0.f;
    #pragma unroll
    for (int s = 1; s < 8; s <<= 1) { offr += __shfl_xor(offr, s); offi += __shfl_xor(offi, s); }
    if (d == 0)
      feat[((size_t)(n * C_ + c)) * F_ + f] = sqrtf(offr * offr + offi * offi) * (1.f / 7.f);
  }
}

// g[n*8+c] = sum_a tanh(feat.proj_w[a] + proj_b[a]) * gvec_w[a] + gvec_b
__global__ __launch_bounds__(256) void proj_kernel(
    const float* __restrict__ feat, const float* __restrict__ pw,
    const float* __restrict__ pb, const float* __restrict__ gw,
    const float* __restrict__ gb, float* __restrict__ g) {
  __shared__ float sfeat[F_];
  __shared__ float red[256];
  int nc = blockIdx.x;
  for (int i = threadIdx.x; i < F_; i += 256) sfeat[i] = feat[(size_t)nc * F_ + i];
  __syncthreads();
  float acc = 0.f;
  for (int a = threadIdx.x; a < A_; a += 256) {
    const float* wrow = pw + (size_t)a * F_;
    float s = 0.f;
    #pragma unroll 4
    for (int ff = 0; ff < F_; ++ff) s += sfeat[ff] * wrow[ff];
    acc += tanhf(s + pb[a]) * gw[a];
  }
  red[threadIdx.x] = acc;
  __syncthreads();
  for (int s = 128; s; s >>= 1) {
    if (threadIdx.x < (unsigned)s) red[threadIdx.x] += red[threadIdx.x + s];
    __syncthreads();
  }
  if (threadIdx.x == 0) g[nc] = red[0] + gb[0];
}

// 8 lanes per (n,f): Gauss-Jordan inverse of Rn_reg, then w = Rn_inv (Rs u) / tr(Rn_inv Rs)
__global__ __launch_bounds__(64) void mvdr_kernel(
    const float* __restrict__ Rs, const float* __restrict__ Rn,
    const float* __restrict__ g, float* __restrict__ wc) {
  int lane = threadIdx.x;
  int item = blockIdx.x * 8 + (lane >> 3);
  int r = lane & 7;
  int base = lane & ~7;
  int n = item / F_;

  const float2* RnM = (const float2*)Rn + (size_t)item * 64;
  const float2* RsM = (const float2*)Rs + (size_t)item * 64;
  float ar[8], ai[8], br[8], bi[8], rsr[8], rsi[8];
  #pragma unroll
  for (int j = 0; j < 8; ++j) {
    float2 v = RnM[r * 8 + j]; ar[j] = v.x; ai[j] = v.y;
    float2 w = RsM[r * 8 + j]; rsr[j] = w.x; rsi[j] = w.y;
    br[j] = (j == r) ? 1.f : 0.f; bi[j] = 0.f;
  }

  #pragma unroll
  for (int k = 0; k < 8; ++k) {
    if (r == k) {
      float dre = ar[k], dim = ai[k];
      float s = 1.f / (dre * dre + dim * dim);
      float cre = dre * s, cim = -dim * s;
      #pragma unroll
      for (int j = 0; j < 8; ++j) {
        float t0 = ar[j] * cre - ai[j] * cim, t1 = ar[j] * cim + ai[j] * cre;
        ar[j] = t0; ai[j] = t1;
        float u0 = br[j] * cre - bi[j] * cim, u1 = br[j] * cim + bi[j] * cre;
        br[j] = u0; bi[j] = u1;
      }
    }
    float par[8], pai[8], pbr[8], pbi[8];
    #pragma unroll
    for (int j = 0; j < 8; ++j) {
      par[j] = __shfl(ar[j], base + k); pai[j] = __shfl(ai[j], base + k);
      pbr[j] = __shfl(br[j], base + k); pbi[j] = __shfl(bi[j], base + k);
    }
    if (r != k) {
      float fre = ar[k], fim = ai[k];
      #pragma unroll
      for (int j = 0; j < 8; ++j) {
        ar[j] -= fre * par[j] - fim * pai[j];
        ai[j] -= fre * pai[j] + fim * par[j];
        br[j] -= fre * pbr[j] - fim * pbi[j];
        bi[j] -= fre * pbi[j] + fim * pbr[j];
      }
    }
  }

  float gv[8];
  #pragma unroll
  for (int d = 0; d < 8; ++d) gv[d] = g[n * 8 + d];
  float gm = gv[0];
  #pragma unroll
  for (int d = 1; d < 8; ++d) gm = fmaxf(gm, gv[d]);
  float u[8], usum = 0.f;
  #pragma unroll
  for (int d = 0; d < 8; ++d) { u[d] = expf(gv[d] - gm); usum += u[d]; }
  float uinv = 1.f / usum;
  #pragma unroll
  for (int d = 0; d < 8; ++d) u[d] *= uinv;

  float avr = 0.f, avi = 0.f;
  #pragma unroll
  for (int d = 0; d < 8; ++d) { avr += rsr[d] * u[d]; avi += rsi[d] * u[d]; }

  float wnr = 0.f, wni = 0.f;
  #pragma unroll
  for (int d = 0; d < 8; ++d) {
    float adr = __shfl(avr, base + d), adi = __shfl(avi, base + d);
    wnr += br[d] * adr - bi[d] * adi;
    wni += br[d] * adi + bi[d] * adr;
  }

  float trr = 0.f, tri = 0.f;
  #pragma unroll
  for (int d = 0; d < 8; ++d) {
    trr += br[d] * rsr[d] + bi[d] * rsi[d];
    tri += bi[d] * rsr[d] - br[d] * rsi[d];
  }
  #pragma unroll
  for (int s = 1; s < 8; s <<= 1) { trr += __shfl_xor(trr, s); tri += __shfl_xor(tri, s); }
  trr += EPSF;

  float den = trr * trr + tri * tri;
  float wre = (wnr * trr + wni * tri) / den;
  float wim = (wni * trr - wnr * tri) / den;
  ((float2*)wc)[(size_t)item * 8 + r] = make_float2(wre, -wim);  // conj(w)
}

// beamform from contiguous x_t: 8f x 128t tile, LDS transpose to (N,T,F,2)
__global__ __launch_bounds__(256) void beamform_xt(
    const float* __restrict__ xt, const float* __restrict__ wc, float* __restrict__ out) {
  __shared__ float lds[128][17];
  int n = blockIdx.z, fb = blockIdx.x * 8, tb = blockIdx.y * 128;
  int tid = threadIdx.x, q = tid & 31, fi = tid >> 5;
  int f = fb + fi, t = tb + q * 4;

  float accr[4] = {0.f, 0.f, 0.f, 0.f}, acci[4] = {0.f, 0.f, 0.f, 0.f};
  if (f < F_ && t < T_) {
    const float4* src = (const float4*)(xt + (((size_t)n * F_ + f) * T_ + t) * 16);
    const float2* wrow = (const float2*)wc + ((size_t)n * F_ + f) * 8;
    float2 w[8];
    #pragma unroll
    for (int c = 0; c < 8; ++c) w[c] = wrow[c];
    #pragma unroll
    for (int dt = 0; dt < 4; ++dt) {
      #pragma unroll
      for (int j = 0; j < 4; ++j) {
        float4 v = src[dt * 4 + j];
        float2 wa = w[2 * j], wb = w[2 * j + 1];
        accr[dt] += wa.x * v.x - wa.y * v.y + wb.x * v.z - wb.y * v.w;
        acci[dt] += wa.x * v.y + wa.y * v.x + wb.x * v.w + wb.y * v.z;
      }
    }
  }
  int row = q * 4, col = fi * 2;
  #pragma unroll
  for (int dt = 0; dt < 4; ++dt) { lds[row + dt][col] = accr[dt]; lds[row + dt][col + 1] = acci[dt]; }
  __syncthreads();

  int col2 = tid & 15, r0 = tid >> 4;
  #pragma unroll
  for (int pass = 0; pass < 8; ++pass) {
    int rr = pass * 16 + r0;
    int tt = tb + rr;
    int ff = fb + (col2 >> 1);
    if (tt < T_ && ff < F_)
      out[(((size_t)n * T_ + tt) * F_ + ff) * 2 + (col2 & 1)] = lds[rr][col2];
  }
}

// legacy beamform reading original strided x (fallback when ws too small for x_t)
__global__ __launch_bounds__(256) void beamform_kernel(
    const float* __restrict__ xr, const float* __restrict__ xi,
    const float* __restrict__ wc, float* __restrict__ out) {
  __shared__ float lds[128][17];
  int n = blockIdx.z, fb = blockIdx.x * 8, tb = blockIdx.y * 128;
  int tid = threadIdx.x, q = tid & 31, fi = tid >> 5;
  int f = fb + fi, t = tb + q * 4;

  float4 br = make_float4(0.f, 0.f, 0.f, 0.f);
  float4 bi = make_float4(0.f, 0.f, 0.f, 0.f);
  if (f < F_ && t < T_) {
    size_t e4 = ((((size_t)(n * C_) * F_ + f) * T_) + t) >> 2;
    const float2* wrow = (const float2*)wc + ((size_t)n * F_ + f) * 8;
    #pragma unroll
    for (int c = 0; c < 8; ++c) {
      float4 a = ((const float4*)xr)[e4 + (size_t)c * CS4];
      float4 b = ((const float4*)xi)[e4 + (size_t)c * CS4];
      float2 w = wrow[c];
      br.x += w.x * a.x - w.y * b.x;  bi.x += w.x * b.x + w.y * a.x;
      br.y += w.x * a.y - w.y * b.y;  bi.y += w.x * b.y + w.y * a.y;
      br.z += w.x * a.z - w.y * b.z;  bi.z += w.x * b.z + w.y * a.z;
      br.w += w.x * a.w - w.y * b.w;  bi.w += w.x * b.w + w.y * a.w;
    }
  }
  int row = q * 4, col = fi * 2;
  lds[row + 0][col] = br.x; lds[row + 0][col + 1] = bi.x;
  lds[row + 1][col] = br.y; lds[row + 1][col + 1] = bi.y;
  lds[row + 2][col] = br.z; lds[row + 2][col + 1] = bi.z;
  lds[row + 3][col] = br.w; lds[row + 3][col + 1] = bi.w;
  __syncthreads();

  int col2 = tid & 15, r0 = tid >> 4;
  #pragma unroll
  for (int pass = 0; pass < 8; ++pass) {
    int rr = pass * 16 + r0;
    int tt = tb + rr;
    int ff = fb + (col2 >> 1);
    if (tt < T_ && ff < F_)
      out[(((size_t)n * T_ + tt) * F_ + ff) * 2 + (col2 & 1)] = lds[rr][col2];
  }
}

extern "C" void kernel_launch(void* const* d_in, const int* in_sizes, int n_in,
                              void* d_out, int out_size, void* d_ws, size_t ws_size,
                              hipStream_t stream) {
  const float* m  = (const float*)d_in[0];
  const float* xr = (const float*)d_in[1];
  const float* xi = (const float*)d_in[2];
  const float* pw = (const float*)d_in[3];
  const float* pb = (const float*)d_in[4];
  const float* gw = (const float*)d_in[5];
  const float* gb = (const float*)d_in[6];
  float* ws  = (float*)d_ws;
  float* out = (float*)d_out;

  float* maxabs = ws + OFF_MAX;
  float* summ   = ws + OFF_SUM;
  float* mt     = ws + OFF_MT;
  float* Rs     = ws + OFF_RS;
  float* Rn     = ws + OFF_RN;
  float* feat   = ws + OFF_FEAT;
  float* g      = ws + OFF_G;
  float* wc     = ws + OFF_WC;
  float* xt     = ws + OFF_XT;
  int have_xt   = (ws_size >= (OFF_XT + XT_SZ) * sizeof(float)) ? 1 : 0;

  hipMemsetAsync(maxabs, 0, 4112 * sizeof(float), stream);  // maxabs + summ contiguous
  hipLaunchKernelGGL(mask_prep, dim3(9, 47, 8), dim3(32, 8), 0, stream, m, mt, maxabs, summ);
  hipLaunchKernelGGL(covar_kernel, dim3(NF), dim3(256), 0, stream,
                     xr, xi, mt, maxabs, summ, Rs, Rn, feat, xt, have_xt);
  hipLaunchKernelGGL(proj_kernel, dim3(64), dim3(256), 0, stream, feat, pw, pb, gw, gb, g);
  hipLaunchKernelGGL(mvdr_kernel, dim3(NF / 8), dim3(64), 0, stream, Rs, Rn, g, wc);
  if (have_xt)
    hipLaunchKernelGGL(beamform_xt, dim3(33, 12, 8), dim3(256), 0, stream, xt, wc, out);
  else
    hipLaunchKernelGGL(beamform_kernel, dim3(33, 12, 8), dim3(256), 0, stream, xr, xi, wc, out);
}

// Round 10
// 365.686 us; speedup vs baseline: 1.6092x; 1.3653x over previous
//
#include <hip/hip_runtime.h>
#include <math.h>

#define EPSF 1.1920928955078125e-07f

constexpr int N_ = 8, C_ = 8, F_ = 257, T_ = 1500, A_ = 512;
constexpr int NF = N_ * F_;          // 2056
constexpr int CS = F_ * T_;          // channel stride in x (385500)
constexpr int CS4 = CS / 4;          // 96375
constexpr int T4 = T_ / 4;           // 375 float4s per (n,f,c) row

// ---- ws layout (float offsets) ----
constexpr size_t OFF_MAX  = 0;                       // 2056
constexpr size_t OFF_SUM  = 2056;                    // 2056
constexpr size_t OFF_MT   = 4352;                    // N*F*T
constexpr size_t OFF_RS   = (OFF_MT + (size_t)N_*F_*T_ + 63) & ~(size_t)63;
constexpr size_t OFF_RN   = OFF_RS + (size_t)NF*64*2;
constexpr size_t OFF_FEAT = OFF_RN + (size_t)NF*64*2;
constexpr size_t OFF_G    = OFF_FEAT + (size_t)N_*C_*F_;
constexpr size_t OFF_WC   = OFF_G + 64;
constexpr size_t OFF_PART = (OFF_WC + (size_t)NF*8*2 + 63) & ~(size_t)63;  // NF*3*128

__device__ __forceinline__ float get4(const float4& v, int k) {
  switch (k) { case 0: return v.x; case 1: return v.y; case 2: return v.z; default: return v.w; }
}

// pair index maps (compile-time): re-slots p=0..35 lower-tri incl diag (c>=d),
// im-slots q=0..27 strict lower-tri (c>d)
constexpr int pc(int p) { int c = 0; while ((c + 1) * (c + 2) / 2 <= p) ++c; return c; }
constexpr int pd(int p) { return p - pc(p) * (pc(p) + 1) / 2; }
constexpr int qc(int q) { int c = 1; while (c * (c + 1) / 2 <= q) ++c; return c; }
constexpr int qd(int q) { return q - qc(q) * (qc(q) - 1) / 2; }

// per-wave slot subset: wave W owns slots W*16..W*16+15 of the 64
// (slot<36: re-pair p=slot; else: im-pair q=slot-36)
template <int W, int I> struct SS {
  static __device__ __forceinline__ void run(const float* re, const float* im, float mk,
                                             float* af, float* aw) {
    constexpr int slot = W * 16 + I;
    if constexpr (slot < 36) {
      constexpr int c = pc(slot), d = pd(slot);
      float pre = re[c] * re[d] + im[c] * im[d];
      af[I] += pre; aw[I] = fmaf(mk, pre, aw[I]);
    } else {
      constexpr int c = qc(slot - 36), d = qd(slot - 36);
      float pim = im[c] * re[d] - re[c] * im[d];
      af[I] += pim; aw[I] = fmaf(mk, pim, aw[I]);
    }
    SS<W, I + 1>::run(re, im, mk, af, aw);
  }
};
template <int W> struct SS<W, 16> {
  static __device__ __forceinline__ void run(const float*, const float*, float, float*, float*) {}
};

template <int W>
__device__ __forceinline__ void acc_chunk(const float4 (*tl)[64], int lane, float* af, float* aw) {
  float4 xv[16];
  #pragma unroll
  for (int s = 0; s < 16; ++s) xv[s] = tl[s][lane];
  float4 mv = tl[16][lane];
  #pragma unroll
  for (int k = 0; k < 4; ++k) {
    float mk = get4(mv, k);
    float re[8], im[8];
    #pragma unroll
    for (int c = 0; c < 8; ++c) { re[c] = get4(xv[c], k); im[c] = get4(xv[8 + c], k); }
    SS<W, 0>::run(re, im, mk, af, aw);
  }
}

__device__ __forceinline__ void gll16(const void* g, void* l) {
  __builtin_amdgcn_global_load_lds((const __attribute__((address_space(1))) unsigned int*)g,
                                   (__attribute__((address_space(3))) unsigned int*)l, 16, 0, 0);
}

// fused transpose + per-(n,f) stats: m[n][t][f] -> mt[n][f][t], maxabs, summ (atomics)
__global__ void mask_prep(const float* __restrict__ m, float* __restrict__ mt,
                          float* __restrict__ maxabs, float* __restrict__ summ) {
  __shared__ float tile[32][33];
  int n = blockIdx.z;
  int f0 = blockIdx.x * 32, t0 = blockIdx.y * 32;
  int tx = threadIdx.x, ty = threadIdx.y;  // 32 x 8
  #pragma unroll
  for (int r = 0; r < 4; ++r) {
    int t = t0 + ty + r * 8, f = f0 + tx;
    tile[ty + r * 8][tx] = (t < T_ && f < F_) ? m[((size_t)n * T_ + t) * F_ + f] : 0.f;
  }
  __syncthreads();
  #pragma unroll
  for (int r = 0; r < 4; ++r) {
    int f = f0 + ty + r * 8, t = t0 + tx;
    float v = tile[tx][ty + r * 8];
    if (t < T_ && f < F_) mt[((size_t)n * F_ + f) * T_ + t] = v;
    float lm = v, ls = v;
    #pragma unroll
    for (int s = 1; s < 32; s <<= 1) {
      lm = fmaxf(lm, __shfl_xor(lm, s));
      ls += __shfl_xor(ls, s);
    }
    if (tx == 0 && f < F_) {
      atomicMax((unsigned int*)(maxabs + n * F_ + f), __float_as_uint(lm));
      atomicAdd(summ + n * F_ + f, ls);
    }
  }
}

// grid (NF, 3): block (item, g) accumulates chunks 2g, 2g+1 (each 64 t-quads;
// chunk 5 partial 55) into 128 partial sums -> part[item][g][0..63=full | 64..127=wt]
__global__ __launch_bounds__(256) void covar_part(
    const float* __restrict__ xr, const float* __restrict__ xi,
    const float* __restrict__ mt, float* __restrict__ part) {
  __shared__ float4 tile[2][17][64];   // [buf][stream 0..7=re,8..15=im,16=mask][t-quad]
  int item = blockIdx.x, g = blockIdx.y, tid = threadIdx.x;
  int wid = tid >> 6, lane = tid & 63;
  int n = item / F_, f = item % F_;
  size_t b4 = (size_t)(n * C_) * CS4 + (size_t)f * T4;
  const float4* pxr = (const float4*)xr;
  const float4* pxi = (const float4*)xi;
  const float4* m4  = (const float4*)(mt + (size_t)item * T_);

  float af[16], aw[16];
  #pragma unroll
  for (int i = 0; i < 16; ++i) { af[i] = 0.f; aw[i] = 0.f; }

  auto stage = [&](int c, float4 (*tl)[64]) {  // full 64-quad chunk, async global->LDS
    #pragma unroll
    for (int j = 0; j < 4; ++j) {
      int s = wid * 4 + j;
      const float4* plane = (s < 8) ? (pxr + b4 + (size_t)s * CS4)
                                    : (pxi + b4 + (size_t)(s - 8) * CS4);
      gll16(plane + c * 64 + lane, &tl[s][0]);
    }
    if (wid == 0) gll16(m4 + c * 64 + lane, &tl[16][0]);
  };
  auto stage5 = [&](float4 (*tl)[64]) {        // chunk 5: 55 of 64 quads valid
    int t4g = 5 * 64 + lane;
    bool ok = t4g < T4;
    float4 z = make_float4(0.f, 0.f, 0.f, 0.f);
    #pragma unroll
    for (int j = 0; j < 4; ++j) {
      int s = wid * 4 + j;
      const float4* plane = (s < 8) ? (pxr + b4 + (size_t)s * CS4)
                                    : (pxi + b4 + (size_t)(s - 8) * CS4);
      tl[s][lane] = ok ? plane[t4g] : z;
    }
    if (wid == 0) tl[16][lane] = ok ? m4[t4g] : z;
  };

  int c0 = g * 2, c1 = g * 2 + 1;
  stage(c0, tile[0]);
  __syncthreads();
  if (c1 < 5) stage(c1, tile[1]); else stage5(tile[1]);
  switch (wid) {
    case 0: acc_chunk<0>(tile[0], lane, af, aw); break;
    case 1: acc_chunk<1>(tile[0], lane, af, aw); break;
    case 2: acc_chunk<2>(tile[0], lane, af, aw); break;
    default: acc_chunk<3>(tile[0], lane, af, aw); break;
  }
  __syncthreads();
  switch (wid) {
    case 0: acc_chunk<0>(tile[1], lane, af, aw); break;
    case 1: acc_chunk<1>(tile[1], lane, af, aw); break;
    case 2: acc_chunk<2>(tile[1], lane, af, aw); break;
    default: acc_chunk<3>(tile[1], lane, af, aw); break;
  }

  #pragma unroll
  for (int s = 1; s < 64; s <<= 1) {
    #pragma unroll
    for (int i = 0; i < 16; ++i) { af[i] += __shfl_xor(af[i], s); aw[i] += __shfl_xor(aw[i], s); }
  }
  if (lane == 0) {
    float* dst = part + ((size_t)item * 3 + g) * 128 + wid * 16;
    #pragma unroll
    for (int i = 0; i < 16; ++i) { dst[i] = af[i]; dst[64 + i] = aw[i]; }
  }
}

// combine 3 partials per (n,f), finalize Rs / Rn_reg / feat. 4 items per 256-block.
__global__ __launch_bounds__(256) void covar_fin(
    const float* __restrict__ part, const float* __restrict__ maxabs,
    const float* __restrict__ summ, float* __restrict__ Rs, float* __restrict__ Rn,
    float* __restrict__ feat) {
  int tid = threadIdx.x;
  int item = blockIdx.x * 4 + (tid >> 6);
  int t64 = tid & 63;
  int n = item / F_, f = item % F_;
  int c = t64 >> 3, d = t64 & 7;
  int cc = max(c, d), dd = min(c, d);
  int p = cc * (cc + 1) / 2 + dd;
  bool offd = (c != d);
  float sgn = (d > c) ? -1.f : 1.f;
  const float* P = part + (size_t)item * 384;

  float sfr = 0.f, swr = 0.f, sfi = 0.f, swi = 0.f;
  #pragma unroll
  for (int gg = 0; gg < 3; ++gg) {
    sfr += P[gg * 128 + p];
    swr += P[gg * 128 + 64 + p];
  }
  if (offd) {
    int q = cc * (cc - 1) / 2 + dd;
    #pragma unroll
    for (int gg = 0; gg < 3; ++gg) {
      sfi += P[gg * 128 + 36 + q];
      swi += P[gg * 128 + 64 + 36 + q];
    }
    sfi *= sgn; swi *= sgn;
  }

  float inv  = 1.f / (maxabs[item] + EPSF);
  float msum = summ[item] * inv;
  float dens = fmaxf(msum, EPSF);
  float denn = fmaxf((float)T_ - msum, EPSF);

  float nsr = swr * inv, nsi = swi * inv;
  float rs_re = nsr / dens, rs_im = nsi / dens;
  float rn_re = (sfr - nsr) / denn, rn_im = (sfi - nsi) / denn;
  if (!offd) rn_re += EPSF;

  ((float2*)Rs)[(size_t)item * 64 + t64] = make_float2(rs_re, rs_im);
  ((float2*)Rn)[(size_t)item * 64 + t64] = make_float2(rn_re, rn_im);

  float offr = offd ? rs_re : 0.f, offi = offd ? rs_im : 0.f;
  #pragma unroll
  for (int s = 1; s < 8; s <<= 1) { offr += __shfl_xor(offr, s); offi += __shfl_xor(offi, s); }
  if (d == 0)
    feat[((size_t)(n * C_ + c)) * F_ + f] = sqrtf(offr * offr + offi * offi) * (1.f / 7.f);
}

// g[n*8+c] = sum_a tanh(feat.proj_w[a] + proj_b[a]) * gvec_w[a] + gvec_b
__global__ __launch_bounds__(256) void proj_kernel(
    const float* __restrict__ feat, const float* __restrict__ pw,
    const float* __restrict__ pb, const float* __restrict__ gw,
    const float* __restrict__ gb, float* __restrict__ g) {
  __shared__ float sfeat[F_];
  __shared__ float red[256];
  int nc = blockIdx.x;
  for (int i = threadIdx.x; i < F_; i += 256) sfeat[i] = feat[(size_t)nc * F_ + i];
  __syncthreads();
  float acc = 0.f;
  for (int a = threadIdx.x; a < A_; a += 256) {
    const float* wrow = pw + (size_t)a * F_;
    float s = 0.f;
    #pragma unroll 16
    for (int ff = 0; ff < F_; ++ff) s += sfeat[ff] * wrow[ff];
    acc += tanhf(s + pb[a]) * gw[a];
  }
  red[threadIdx.x] = acc;
  __syncthreads();
  for (int s = 128; s; s >>= 1) {
    if (threadIdx.x < (unsigned)s) red[threadIdx.x] += red[threadIdx.x + s];
    __syncthreads();
  }
  if (threadIdx.x == 0) g[nc] = red[0] + gb[0];
}

// 8 lanes per (n,f): Gauss-Jordan inverse of Rn_reg, then w = Rn_inv (Rs u) / tr(Rn_inv Rs)
__global__ __launch_bounds__(64) void mvdr_kernel(
    const float* __restrict__ Rs, const float* __restrict__ Rn,
    const float* __restrict__ g, float* __restrict__ wc) {
  int lane = threadIdx.x;
  int item = blockIdx.x * 8 + (lane >> 3);
  int r = lane & 7;
  int base = lane & ~7;
  int n = item / F_;

  const float2* RnM = (const float2*)Rn + (size_t)item * 64;
  const float2* RsM = (const float2*)Rs + (size_t)item * 64;
  float ar[8], ai[8], br[8], bi[8], rsr[8], rsi[8];
  #pragma unroll
  for (int j = 0; j < 8; ++j) {
    float2 v = RnM[r * 8 + j]; ar[j] = v.x; ai[j] = v.y;
    float2 w = RsM[r * 8 + j]; rsr[j] = w.x; rsi[j] = w.y;
    br[j] = (j == r) ? 1.f : 0.f; bi[j] = 0.f;
  }

  #pragma unroll
  for (int k = 0; k < 8; ++k) {
    if (r == k) {
      float dre = ar[k], dim = ai[k];
      float s = 1.f / (dre * dre + dim * dim);
      float cre = dre * s, cim = -dim * s;
      #pragma unroll
      for (int j = 0; j < 8; ++j) {
        float t0 = ar[j] * cre - ai[j] * cim, t1 = ar[j] * cim + ai[j] * cre;
        ar[j] = t0; ai[j] = t1;
        float u0 = br[j] * cre - bi[j] * cim, u1 = br[j] * cim + bi[j] * cre;
        br[j] = u0; bi[j] = u1;
      }
    }
    float par[8], pai[8], pbr[8], pbi[8];
    #pragma unroll
    for (int j = 0; j < 8; ++j) {
      par[j] = __shfl(ar[j], base + k); pai[j] = __shfl(ai[j], base + k);
      pbr[j] = __shfl(br[j], base + k); pbi[j] = __shfl(bi[j], base + k);
    }
    if (r != k) {
      float fre = ar[k], fim = ai[k];
      #pragma unroll
      for (int j = 0; j < 8; ++j) {
        ar[j] -= fre * par[j] - fim * pai[j];
        ai[j] -= fre * pai[j] + fim * par[j];
        br[j] -= fre * pbr[j] - fim * pbi[j];
        bi[j] -= fre * pbi[j] + fim * pbr[j];
      }
    }
  }

  float gv[8];
  #pragma unroll
  for (int d = 0; d < 8; ++d) gv[d] = g[n * 8 + d];
  float gm = gv[0];
  #pragma unroll
  for (int d = 1; d < 8; ++d) gm = fmaxf(gm, gv[d]);
  float u[8], usum = 0.f;
  #pragma unroll
  for (int d = 0; d < 8; ++d) { u[d] = expf(gv[d] - gm); usum += u[d]; }
  float uinv = 1.f / usum;
  #pragma unroll
  for (int d = 0; d < 8; ++d) u[d] *= uinv;

  float avr = 0.f, avi = 0.f;
  #pragma unroll
  for (int d = 0; d < 8; ++d) { avr += rsr[d] * u[d]; avi += rsi[d] * u[d]; }

  float wnr = 0.f, wni = 0.f;
  #pragma unroll
  for (int d = 0; d < 8; ++d) {
    float adr = __shfl(avr, base + d), adi = __shfl(avi, base + d);
    wnr += br[d] * adr - bi[d] * adi;
    wni += br[d] * adi + bi[d] * adr;
  }

  float trr = 0.f, tri = 0.f;
  #pragma unroll
  for (int d = 0; d < 8; ++d) {
    trr += br[d] * rsr[d] + bi[d] * rsi[d];
    tri += bi[d] * rsr[d] - br[d] * rsi[d];
  }
  #pragma unroll
  for (int s = 1; s < 8; s <<= 1) { trr += __shfl_xor(trr, s); tri += __shfl_xor(tri, s); }
  trr += EPSF;

  float den = trr * trr + tri * tri;
  float wre = (wnr * trr + wni * tri) / den;
  float wim = (wni * trr - wnr * tri) / den;
  ((float2*)wc)[(size_t)item * 8 + r] = make_float2(wre, -wim);  // conj(w)
}

// beamform reading original strided x: 8f x 128t tile, float4 loads, LDS transpose
__global__ __launch_bounds__(256) void beamform_kernel(
    const float* __restrict__ xr, const float* __restrict__ xi,
    const float* __restrict__ wc, float* __restrict__ out) {
  __shared__ float lds[128][17];
  int n = blockIdx.z, fb = blockIdx.x * 8, tb = blockIdx.y * 128;
  int tid = threadIdx.x, q = tid & 31, fi = tid >> 5;
  int f = fb + fi, t = tb + q * 4;

  float4 br = make_float4(0.f, 0.f, 0.f, 0.f);
  float4 bi = make_float4(0.f, 0.f, 0.f, 0.f);
  if (f < F_ && t < T_) {
    size_t e4 = ((((size_t)(n * C_) * F_ + f) * T_) + t) >> 2;
    const float2* wrow = (const float2*)wc + ((size_t)n * F_ + f) * 8;
    #pragma unroll
    for (int c = 0; c < 8; ++c) {
      float4 a = ((const float4*)xr)[e4 + (size_t)c * CS4];
      float4 b = ((const float4*)xi)[e4 + (size_t)c * CS4];
      float2 w = wrow[c];
      br.x += w.x * a.x - w.y * b.x;  bi.x += w.x * b.x + w.y * a.x;
      br.y += w.x * a.y - w.y * b.y;  bi.y += w.x * b.y + w.y * a.y;
      br.z += w.x * a.z - w.y * b.z;  bi.z += w.x * b.z + w.y * a.z;
      br.w += w.x * a.w - w.y * b.w;  bi.w += w.x * b.w + w.y * a.w;
    }
  }
  int row = q * 4, col = fi * 2;
  lds[row + 0][col] = br.x; lds[row + 0][col + 1] = bi.x;
  lds[row + 1][col] = br.y; lds[row + 1][col + 1] = bi.y;
  lds[row + 2][col] = br.z; lds[row + 2][col + 1] = bi.z;
  lds[row + 3][col] = br.w; lds[row + 3][col + 1] = bi.w;
  __syncthreads();

  int col2 = tid & 15, r0 = tid >> 4;
  #pragma unroll
  for (int pass = 0; pass < 8; ++pass) {
    int rr = pass * 16 + r0;
    int tt = tb + rr;
    int ff = fb + (col2 >> 1);
    if (tt < T_ && ff < F_)
      out[(((size_t)n * T_ + tt) * F_ + ff) * 2 + (col2 & 1)] = lds[rr][col2];
  }
}

extern "C" void kernel_launch(void* const* d_in, const int* in_sizes, int n_in,
                              void* d_out, int out_size, void* d_ws, size_t ws_size,
                              hipStream_t stream) {
  const float* m  = (const float*)d_in[0];
  const float* xr = (const float*)d_in[1];
  const float* xi = (const float*)d_in[2];
  const float* pw = (const float*)d_in[3];
  const float* pb = (const float*)d_in[4];
  const float* gw = (const float*)d_in[5];
  const float* gb = (const float*)d_in[6];
  float* ws  = (float*)d_ws;
  float* out = (float*)d_out;

  float* maxabs = ws + OFF_MAX;
  float* summ   = ws + OFF_SUM;
  float* mt     = ws + OFF_MT;
  float* Rs     = ws + OFF_RS;
  float* Rn     = ws + OFF_RN;
  float* feat   = ws + OFF_FEAT;
  float* g      = ws + OFF_G;
  float* wc     = ws + OFF_WC;
  float* part   = ws + OFF_PART;

  hipMemsetAsync(maxabs, 0, 4112 * sizeof(float), stream);  // maxabs + summ contiguous
  hipLaunchKernelGGL(mask_prep, dim3(9, 47, 8), dim3(32, 8), 0, stream, m, mt, maxabs, summ);
  hipLaunchKernelGGL(covar_part, dim3(NF, 3), dim3(256), 0, stream, xr, xi, mt, part);
  hipLaunchKernelGGL(covar_fin, dim3(NF / 4), dim3(256), 0, stream,
                     part, maxabs, summ, Rs, Rn, feat);
  hipLaunchKernelGGL(proj_kernel, dim3(64), dim3(256), 0, stream, feat, pw, pb, gw, gb, g);
  hipLaunchKernelGGL(mvdr_kernel, dim3(NF / 8), dim3(64), 0, stream, Rs, Rn, g, wc);
  hipLaunchKernelGGL(beamform_kernel, dim3(33, 12, 8), dim3(256), 0, stream, xr, xi, wc, out);
}